// Round 4
// baseline (239.129 us; speedup 1.0000x reference)
//
#include <hip/hip_runtime.h>
#include <hip/hip_bf16.h>

#define NN 8192
#define TOTD 128
#define HIDD 64
#define NHEAD 4
#define DHD 32
#define NCQ 16                // column splits for attention kernels
#define JPB (NN / 32 / NCQ)   // 16 column-tiles (jt) per block

typedef __attribute__((ext_vector_type(8))) short short8;
typedef __attribute__((ext_vector_type(4))) float f32x4;

__device__ __forceinline__ short f2b(float f) {      // RTNE (for operands)
  unsigned u = __builtin_bit_cast(unsigned, f);
  u += 0x7fff + ((u >> 16) & 1);
  return (short)(u >> 16);
}
__device__ __forceinline__ short f2b_fast(float f) { // round-half-up (P only, P>=0)
  unsigned u = __builtin_bit_cast(unsigned, f);
  return (short)((u + 0x8000u) >> 16);
}
__device__ __forceinline__ float fexp2(float x) {
#if __has_builtin(__builtin_amdgcn_exp2f)
  return __builtin_amdgcn_exp2f(x);
#else
  return exp2f(x);
#endif
}

// async global->LDS, 16B per lane; lds dest must be wave-uniform base + lane*16
__device__ __forceinline__ void gl_lds16(const short* g, short* l) {
  __builtin_amdgcn_global_load_lds(
      (const __attribute__((address_space(1))) void*)g,
      (__attribute__((address_space(3))) void*)l, 16, 0, 0);
}

// ---------------- K1: xb fragments: xb[jt][cg][lane][8] ----------------------
__global__ void k_build_xfrag(const float* __restrict__ in, const float* __restrict__ hx,
                              short* __restrict__ xb) {
  int i = blockIdx.x * 256 + threadIdx.x;   // over NN*TOTD, t-fastest
  int n = i >> 7;
  int t = i & 127;
  float v = (t < 64) ? in[n * 64 + t] : hx[n * 64 + (t - 64)];
  int jt = n >> 5, kk = n & 31, cg = t >> 4;
  int l = ((kk >> 3) << 4) | (t & 15);
  xb[(((size_t)jt * 8 + cg) << 9) + (l << 3) + (kk & 7)] = f2b(v);
}

// ---------------- K2: q,k projections (q pre-scaled by log2e/sqrt(DH)) -------
__global__ void k_qk(const float* __restrict__ in, const float* __restrict__ hx,
                     const float* __restrict__ Wq, const float* __restrict__ Wk,
                     short* __restrict__ qb, short* __restrict__ kb) {
  __shared__ float xr[TOTD];
  int n = blockIdx.x;
  int tid = threadIdx.x;
  if (tid < TOTD) xr[tid] = (tid < 64) ? in[n * 64 + tid] : hx[n * 64 + (tid - 64)];
  __syncthreads();
  int which = tid >> 7;          // 0 -> q, 1 -> k
  int h = (tid >> 5) & 3;
  int d = tid & 31;
  const float* W = (which ? Wk : Wq) + h * TOTD * DHD + d;
  float acc = 0.f;
#pragma unroll
  for (int t = 0; t < TOTD; ++t) acc += xr[t] * W[t * DHD];
  int l = ((d >> 3) << 4) | (n & 15);
  if (!which) {
    acc *= 0.25503486f;          // log2(e) / sqrt(32)
    qb[(((size_t)(n >> 4) * 4 + h) << 9) + (l << 3) + (d & 7)] = f2b(acc);
  } else {
    kb[((((size_t)(n >> 5) * 4 + h) * 2 + ((n >> 4) & 1)) << 9) + (l << 3) + (d & 7)] = f2b(acc);
  }
}

// ---------------- K3a: partial softmax denominators --------------------------
__global__ __launch_bounds__(256, 8) void k_denom(
    const short* __restrict__ qb, const short* __restrict__ kb,
    float* __restrict__ lpart_g) {
  __shared__ short kbuf[8 * 512];
  const int tid = threadIdx.x;
  const int w = tid >> 6, l = tid & 63;
  const int row16 = l & 15, grp = l >> 4;
  const int r0 = blockIdx.x * 64 + w * 16;
  const int rtile = blockIdx.x * 4 + w;
  const int jt0 = blockIdx.y * JPB;
  const f32x4 zero4 = {0.f, 0.f, 0.f, 0.f};

  short8 qf[NHEAD];
#pragma unroll
  for (int h = 0; h < NHEAD; ++h)
    qf[h] = *(const short8*)&qb[(((size_t)rtile * 4 + h) << 9) + l * 8];

  float acc[NHEAD][4];
#pragma unroll
  for (int h = 0; h < NHEAD; ++h)
#pragma unroll
    for (int r = 0; r < 4; ++r) acc[h][r] = 0.f;

  for (int j = 0; j < JPB; ++j) {
    int jt = jt0 + j;
#pragma unroll
    for (int c = w * 2; c < w * 2 + 2; ++c)
      gl_lds16(kb + (((size_t)jt * 8 + c) << 9) + l * 8, &kbuf[c * 512]);
    __syncthreads();
#pragma unroll
    for (int hs = 0; hs < 8; ++hs) {
      short8 kf = *(const short8*)&kbuf[hs * 512 + l * 8];
      f32x4 s = __builtin_amdgcn_mfma_f32_16x16x32_bf16(qf[hs >> 1], kf, zero4, 0, 0, 0);
#pragma unroll
      for (int r = 0; r < 4; ++r) acc[hs >> 1][r] += fexp2(s[r]);
    }
    __syncthreads();
  }
#pragma unroll
  for (int m = 1; m < 16; m <<= 1)
#pragma unroll
    for (int h = 0; h < NHEAD; ++h)
#pragma unroll
      for (int r = 0; r < 4; ++r) acc[h][r] += __shfl_xor(acc[h][r], m, 64);

  if (row16 == 0) {
#pragma unroll
    for (int h = 0; h < NHEAD; ++h)
#pragma unroll
      for (int r = 0; r < 4; ++r)
        lpart_g[((size_t)blockIdx.y * NHEAD + h) * NN + r0 + grp * 4 + r] = acc[h][r];
  }
}

// ---------------- K3b: linv = 0.25 / sum of NCQ partials ---------------------
__global__ void k_linv(const float* __restrict__ lpart_g, float* __restrict__ linv_g) {
  int i = blockIdx.x * 256 + threadIdx.x;      // over NHEAD*NN
  float s = 0.f;
#pragma unroll
  for (int q = 0; q < NCQ; ++q) s += lpart_g[(size_t)q * NHEAD * NN + i];
  linv_g[i] = 0.25f / s;
}

// ---------------- K3c: P formation + ax partials -----------------------------
__global__ __launch_bounds__(256, 5) void k_pv1(
    const short* __restrict__ qb, const short* __restrict__ kb,
    const short* __restrict__ xb, const float* __restrict__ linv_g,
    float* __restrict__ axq) {
  __shared__ short kxbuf[16 * 512];
  __shared__ short Plds[4][16][40];   // rows padded to 80B: 2-way conflicts only
  const int tid = threadIdx.x;
  const int w = tid >> 6, l = tid & 63;
  const int row16 = l & 15, grp = l >> 4;
  const int r0 = blockIdx.x * 64 + w * 16;
  const int rtile = blockIdx.x * 4 + w;
  const int jt0 = blockIdx.y * JPB;
  const f32x4 zero4 = {0.f, 0.f, 0.f, 0.f};

  short8 qf[NHEAD];
#pragma unroll
  for (int h = 0; h < NHEAD; ++h)
    qf[h] = *(const short8*)&qb[(((size_t)rtile * 4 + h) << 9) + l * 8];
  float linv[NHEAD][4];
#pragma unroll
  for (int h = 0; h < NHEAD; ++h)
#pragma unroll
    for (int r = 0; r < 4; ++r) linv[h][r] = linv_g[h * NN + r0 + grp * 4 + r];

  f32x4 axa[8];
#pragma unroll
  for (int cg = 0; cg < 8; ++cg) axa[cg] = zero4;

  for (int j = 0; j < JPB; ++j) {
    int jt = jt0 + j;
    // chunks 0..7 = K frags, 8..15 = X frags; each wave stages 4
#pragma unroll
    for (int c = w * 4; c < w * 4 + 4; ++c) {
      const short* src = (c < 8) ? kb + (((size_t)jt * 8 + c) << 9) + l * 8
                                 : xb + (((size_t)jt * 8 + (c - 8)) << 9) + l * 8;
      gl_lds16(src, &kxbuf[c * 512]);
    }
    __syncthreads();
#pragma unroll
    for (int sub = 0; sub < 2; ++sub) {
      float p[4] = {0.f, 0.f, 0.f, 0.f};
#pragma unroll
      for (int h = 0; h < NHEAD; ++h) {
        short8 kf = *(const short8*)&kxbuf[(h * 2 + sub) * 512 + l * 8];
        f32x4 s = __builtin_amdgcn_mfma_f32_16x16x32_bf16(qf[h], kf, zero4, 0, 0, 0);
#pragma unroll
        for (int r = 0; r < 4; ++r) p[r] += fexp2(s[r]) * linv[h][r];
      }
#pragma unroll
      for (int r = 0; r < 4; ++r)
        Plds[w][grp * 4 + r][sub * 16 + row16] = f2b_fast(p[r]);
    }
    short8 pa = *(short8*)&Plds[w][row16][grp * 8];
#pragma unroll
    for (int cg = 0; cg < 8; ++cg) {
      short8 xv = *(const short8*)&kxbuf[(8 + cg) * 512 + l * 8];
      axa[cg] = __builtin_amdgcn_mfma_f32_16x16x32_bf16(pa, xv, axa[cg], 0, 0, 0);
    }
    __syncthreads();
  }
#pragma unroll
  for (int cg = 0; cg < 8; ++cg)
#pragma unroll
    for (int r = 0; r < 4; ++r)
      axq[(size_t)blockIdx.y * NN * TOTD + (size_t)(r0 + grp * 4 + r) * TOTD + cg * 16 + row16] =
          axa[cg][r];
}

// ---------------- K4: ax reduce + r,z gates; v2 fragments --------------------
__global__ void k_rz(const float* __restrict__ axq, const float* __restrict__ hx,
                     const float* __restrict__ Wr, const float* __restrict__ br,
                     const float* __restrict__ Wz, const float* __restrict__ bz,
                     float* __restrict__ ax, float* __restrict__ z,
                     short* __restrict__ v2f) {
  __shared__ float axs[2][TOTD];
  int tid = threadIdx.x;
  int rr = tid >> 7;
  int c2 = tid & 127;
  int n = blockIdx.x * 2 + rr;
  float s = 0.f;
#pragma unroll
  for (int q = 0; q < NCQ; ++q) s += axq[(size_t)q * NN * TOTD + (size_t)n * TOTD + c2];
  axs[rr][c2] = s;
  ax[(size_t)n * TOTD + c2] = s;
  __syncthreads();
  bool isz = c2 >= HIDD;
  int c = c2 & (HIDD - 1);
  const float* W = isz ? Wz : Wr;
  float acc = isz ? bz[c] : br[c];
#pragma unroll
  for (int t = 0; t < TOTD; ++t) acc += axs[rr][t] * W[t * HIDD + c];
  float sg = 1.f / (1.f + __expf(-acc));
  if (isz) {
    z[n * HIDD + c] = sg;
  } else {
    int jt = n >> 5, kk = n & 31, cg = c >> 4;
    int ll = ((kk >> 3) << 4) | (c & 15);
    v2f[(((size_t)jt * 4 + cg) << 9) + (ll << 3) + (kk & 7)] = f2b(sg * hx[n * HIDD + c]);
  }
}

// ---------------- K5: a2 partials, recomputing P -----------------------------
__global__ __launch_bounds__(256, 5) void k_pv2(
    const short* __restrict__ qb, const short* __restrict__ kb,
    const short* __restrict__ v2f, const float* __restrict__ linv_g,
    float* __restrict__ a2q) {
  __shared__ short kvbuf[12 * 512];
  __shared__ short Plds[4][16][40];
  const int tid = threadIdx.x;
  const int w = tid >> 6, l = tid & 63;
  const int row16 = l & 15, grp = l >> 4;
  const int r0 = blockIdx.x * 64 + w * 16;
  const int rtile = blockIdx.x * 4 + w;
  const int jt0 = blockIdx.y * JPB;
  const f32x4 zero4 = {0.f, 0.f, 0.f, 0.f};

  short8 qf[NHEAD];
#pragma unroll
  for (int h = 0; h < NHEAD; ++h)
    qf[h] = *(const short8*)&qb[(((size_t)rtile * 4 + h) << 9) + l * 8];
  float linv[NHEAD][4];
#pragma unroll
  for (int h = 0; h < NHEAD; ++h)
#pragma unroll
    for (int r = 0; r < 4; ++r) linv[h][r] = linv_g[h * NN + r0 + grp * 4 + r];

  f32x4 a2a[4];
#pragma unroll
  for (int cg = 0; cg < 4; ++cg) a2a[cg] = zero4;

  for (int j = 0; j < JPB; ++j) {
    int jt = jt0 + j;
    // chunks 0..7 = K frags, 8..11 = V frags; each wave stages 3
#pragma unroll
    for (int c = w * 3; c < w * 3 + 3; ++c) {
      const short* src = (c < 8) ? kb + (((size_t)jt * 8 + c) << 9) + l * 8
                                 : v2f + (((size_t)jt * 4 + (c - 8)) << 9) + l * 8;
      gl_lds16(src, &kvbuf[c * 512]);
    }
    __syncthreads();
#pragma unroll
    for (int sub = 0; sub < 2; ++sub) {
      float p[4] = {0.f, 0.f, 0.f, 0.f};
#pragma unroll
      for (int h = 0; h < NHEAD; ++h) {
        short8 kf = *(const short8*)&kvbuf[(h * 2 + sub) * 512 + l * 8];
        f32x4 s = __builtin_amdgcn_mfma_f32_16x16x32_bf16(qf[h], kf, zero4, 0, 0, 0);
#pragma unroll
        for (int r = 0; r < 4; ++r) p[r] += fexp2(s[r]) * linv[h][r];
      }
#pragma unroll
      for (int r = 0; r < 4; ++r)
        Plds[w][grp * 4 + r][sub * 16 + row16] = f2b_fast(p[r]);
    }
    short8 pa = *(short8*)&Plds[w][row16][grp * 8];
#pragma unroll
    for (int cg = 0; cg < 4; ++cg) {
      short8 vv = *(const short8*)&kvbuf[(8 + cg) * 512 + l * 8];
      a2a[cg] = __builtin_amdgcn_mfma_f32_16x16x32_bf16(pa, vv, a2a[cg], 0, 0, 0);
    }
    __syncthreads();
  }
#pragma unroll
  for (int cg = 0; cg < 4; ++cg)
#pragma unroll
    for (int r = 0; r < 4; ++r)
      a2q[(size_t)blockIdx.y * NN * HIDD + (size_t)(r0 + grp * 4 + r) * HIDD + cg * 16 + row16] =
          a2a[cg][r];
}

// ---------------- K6: a2 reduce + GRU epilogue -------------------------------
__global__ __launch_bounds__(256) void k_final(
    const float* __restrict__ a2q, const float* __restrict__ ax,
    const float* __restrict__ hx, const float* __restrict__ Wh,
    const float* __restrict__ bh, const float* __restrict__ z,
    float* __restrict__ out) {
  __shared__ float Whs[TOTD * HIDD];
  __shared__ float a2s[16][HIDD];
  const int tid = threadIdx.x;
  const int r0 = blockIdx.x * 16;

  for (int i = tid; i < TOTD * HIDD; i += 256) Whs[i] = Wh[i];
  for (int i = tid; i < 16 * HIDD; i += 256) {
    int rw = i >> 6, c = i & 63;
    size_t gi = (size_t)(r0 + rw) * HIDD + c;
    float s = 0.f;
#pragma unroll
    for (int q = 0; q < NCQ; ++q) s += a2q[(size_t)q * NN * HIDD + gi];
    a2s[rw][c] = s;
  }
  __syncthreads();
  for (int o = tid; o < 16 * HIDD; o += 256) {
    int rw = o >> 6, c = o & 63;
    const float* axrow = &ax[(size_t)(r0 + rw) * TOTD];
    float acc = bh[c];
#pragma unroll
    for (int t = 0; t < 64; ++t) acc += axrow[t] * Whs[t * HIDD + c];
#pragma unroll
    for (int t = 0; t < 64; ++t) acc += a2s[rw][t] * Whs[(64 + t) * HIDD + c];
    float hval = tanhf(acc);
    size_t gi = (size_t)(r0 + rw) * HIDD + c;
    float zz = z[gi];
    out[gi] = zz * hx[gi] + (1.f - zz) * hval;
  }
}

extern "C" void kernel_launch(void* const* d_in, const int* in_sizes, int n_in,
                              void* d_out, int out_size, void* d_ws, size_t ws_size,
                              hipStream_t stream) {
  const float* in = (const float*)d_in[0];
  const float* hx = (const float*)d_in[1];
  const float* Wq = (const float*)d_in[2];
  const float* Wk = (const float*)d_in[3];
  const float* Wr = (const float*)d_in[4];
  const float* br = (const float*)d_in[5];
  const float* Wz = (const float*)d_in[6];
  const float* bz = (const float*)d_in[7];
  const float* Wh = (const float*)d_in[8];
  const float* bh = (const float*)d_in[9];

  const size_t MB = 1ull << 20;
  char* ws = (char*)d_ws;
  short* qb    = (short*)(ws + 0 * MB);          // 2 MB
  short* kb    = (short*)(ws + 2 * MB);          // 2 MB
  short* xb    = (short*)(ws + 4 * MB);          // 2 MB
  float* linv  = (float*)(ws + 6 * MB);          // 128 KB
  float* lpart = (float*)(ws + 7 * MB);          // 2 MB (NCQ slices)
  float* ax    = (float*)(ws + 10 * MB);         // 4 MB
  float* z     = (float*)(ws + 14 * MB);         // 2 MB
  short* v2f   = (short*)(ws + 16 * MB);         // 1 MB
  float* axq   = (float*)(ws + 20 * MB);         // 64 MB (NCQ slices)
  float* a2q   = (float*)(ws + 84 * MB);         // 32 MB (NCQ slices)
  float* out   = (float*)d_out;

  k_build_xfrag<<<dim3((NN * TOTD) / 256), dim3(256), 0, stream>>>(in, hx, xb);
  k_qk<<<dim3(NN), dim3(256), 0, stream>>>(in, hx, Wq, Wk, qb, kb);
  k_denom<<<dim3(NN / 64, NCQ), dim3(256), 0, stream>>>(qb, kb, lpart);
  k_linv<<<dim3((NHEAD * NN) / 256), dim3(256), 0, stream>>>(lpart, linv);
  k_pv1<<<dim3(NN / 64, NCQ), dim3(256), 0, stream>>>(qb, kb, xb, linv, axq);
  k_rz<<<dim3(NN / 2), dim3(256), 0, stream>>>(axq, hx, Wr, br, Wz, bz, ax, z, v2f);
  k_pv2<<<dim3(NN / 64, NCQ), dim3(256), 0, stream>>>(qb, kb, v2f, linv, a2q);
  k_final<<<dim3(NN / 16), dim3(256), 0, stream>>>(a2q, ax, hx, Wh, bh, z, out);
}